// Round 6
// baseline (173.650 us; speedup 1.0000x reference)
//
#include <hip/hip_runtime.h>
#include <math.h>

// Problem constants (from reference): B,H,K,L,V = 4096,1024,10,64,80
constexpr int Bn = 4096;
constexpr int Hn = 1024;
constexpr int Kn = 10;
constexpr int Ln = 64;
constexpr int Vn = 80;
constexpr int NJ = 3 * Kn;   // 30
constexpr int RA = 4;        // batch rows per block (kernel A)
constexpr int RB = 4;        // batch rows per block (kernel B)

// MEASUREMENT ROUND: kernels identical to round 5. kernel_launch runs B three
// times (identical deterministic work per launch) so dur_us = base + 2*B_warm,
// isolating kernel B's duration from the ~102 us fixed harness reset.

// ---------------- Kernel A: phi[b][l] = sum_k alpha*exp(-beta*(kappa-l)^2) ----
__global__ __launch_bounds__(256) void phi_kernel(
    const float* __restrict__ x,      // [B,H]
    const float* __restrict__ W,      // [H,3K]
    const float* __restrict__ bias,   // [3K]
    float* __restrict__ phi)          // [B,L]  (workspace)
{
    __shared__ __align__(16) float xs[RA * Hn];   // 16 KB
    __shared__ float part[RA * 256];              // 4 KB
    __shared__ float abk[RA * NJ];                // 480 B

    float4* xs4 = (float4*)xs;
    const int t    = threadIdx.x;
    const int row0 = blockIdx.x * RA;

    // Stage x rows into LDS (coalesced float4)
    const float4* x4 = (const float4*)x;
#pragma unroll
    for (int r = 0; r < RA; ++r)
        xs4[r * (Hn / 4) + t] = x4[(size_t)(row0 + r) * (Hn / 4) + t];
    __syncthreads();

    // GEMM partials: thread (j = t&31, g = t>>5) covers h in [128g, 128g+128)
    const int j = t & 31;
    const int g = t >> 5;
    float acc0 = 0.f, acc1 = 0.f, acc2 = 0.f, acc3 = 0.f;
    if (j < NJ) {
        const float* Wp = W + j;
        const int h0 = g * 128;
#pragma unroll 8
        for (int ii = 0; ii < 128; ii += 4) {
            const int h  = h0 + ii;
            const int h4 = h >> 2;
            float4 xa = xs4[0 * (Hn / 4) + h4];   // broadcast across j-lanes
            float4 xb = xs4[1 * (Hn / 4) + h4];
            float4 xc = xs4[2 * (Hn / 4) + h4];
            float4 xd = xs4[3 * (Hn / 4) + h4];
            float w0 = Wp[(h + 0) * NJ];
            float w1 = Wp[(h + 1) * NJ];
            float w2 = Wp[(h + 2) * NJ];
            float w3 = Wp[(h + 3) * NJ];
            acc0 += w0 * xa.x + w1 * xa.y + w2 * xa.z + w3 * xa.w;
            acc1 += w0 * xb.x + w1 * xb.y + w2 * xb.z + w3 * xb.w;
            acc2 += w0 * xc.x + w1 * xc.y + w2 * xc.z + w3 * xc.w;
            acc3 += w0 * xd.x + w1 * xd.y + w2 * xd.z + w3 * xd.w;
        }
    }
    part[0 * 256 + g * 32 + j] = acc0;
    part[1 * 256 + g * 32 + j] = acc1;
    part[2 * 256 + g * 32 + j] = acc2;
    part[3 * 256 + g * 32 + j] = acc3;
    __syncthreads();

    // Reduce partials, add bias, exp
    if (t < RA * NJ) {  // 120 threads
        const int r = t / NJ, jj = t % NJ;
        float s = bias[jj];
#pragma unroll
        for (int gg = 0; gg < 8; ++gg) s += part[r * 256 + gg * 32 + jj];
        abk[r * NJ + jj] = __expf(s);
    }
    __syncthreads();

    // phi, stored straight to global: address = row0*64 + t (fully coalesced)
    {
        const int r = t >> 6, l = t & 63;
        const float lf = (float)l;
        const float* ab = abk + r * NJ;
        float ph = 0.f;
#pragma unroll
        for (int k = 0; k < Kn; ++k) {
            float a  = ab[k];
            float bt = ab[Kn + k];
            float kp = ab[2 * Kn + k];
            float d  = kp - lf;
            ph += a * __expf(-bt * d * d);
        }
        phi[(size_t)row0 * Ln + t] = ph;
    }
}

// ---------------- Kernel B: out[b][v] = sum_l phi[b][l] * chars[b][l][v] ------
__global__ __launch_bounds__(256, 4) void window_kernel(
    const float* __restrict__ chars,  // [B,L,V]
    const float* __restrict__ phi,    // [B,L]
    float* __restrict__ out)          // [B,V]
{
    __shared__ float  phis[RB * Ln];        // 256 floats = 1 KB
    __shared__ float4 cpart[2][RB][20];     // 2.5 KB

    const int t    = threadIdx.x;
    const int row0 = blockIdx.x * RB;

    // Stage 4 phi rows (256 floats), one coalesced load
    phis[t] = phi[(size_t)row0 * Ln + t];
    __syncthreads();

    const int v4 = t & 31;          // float4 column, active if < 20
    const int r  = (t >> 5) & 3;    // row within block
    const int hl = t >> 7;          // which l-half
    if (v4 < 20) {
        const int b = row0 + r;
        const float4* c4 = (const float4*)chars + (size_t)b * (Ln * Vn / 4) + v4;
        const float* ph = phis + r * Ln;
        float4 acc = make_float4(0.f, 0.f, 0.f, 0.f);
        const int l0 = hl * 32;
#pragma unroll
        for (int i = 0; i < 32; ++i) {
            const int l = l0 + i;
            float4 c = c4[l * (Vn / 4)];
            float  p = ph[l];
            acc.x += p * c.x; acc.y += p * c.y; acc.z += p * c.z; acc.w += p * c.w;
        }
        cpart[hl][r][v4] = acc;
    }
    __syncthreads();

    if (t < RB * 20) {  // 80 threads: combine halves, store
        const int rr = t / 20, vv = t % 20;
        float4 a0 = cpart[0][rr][vv];
        float4 a1 = cpart[1][rr][vv];
        float4 s = make_float4(a0.x + a1.x, a0.y + a1.y, a0.z + a1.z, a0.w + a1.w);
        ((float4*)out)[(size_t)(row0 + rr) * (Vn / 4) + vv] = s;
    }
}

extern "C" void kernel_launch(void* const* d_in, const int* in_sizes, int n_in,
                              void* d_out, int out_size, void* d_ws, size_t ws_size,
                              hipStream_t stream) {
    const float* x     = (const float*)d_in[0];
    const float* chars = (const float*)d_in[1];
    const float* W     = (const float*)d_in[2];
    const float* bias  = (const float*)d_in[3];
    float* out = (float*)d_out;
    float* phi = (float*)d_ws;   // 4096*64*4 = 1 MB

    phi_kernel<<<Bn / RA, 256, 0, stream>>>(x, W, bias, phi);
    // Measurement: run B three times (identical deterministic work each time).
    // dur_us_new - dur_us_R5 = 2 * B_warm.
    window_kernel<<<Bn / RB, 256, 0, stream>>>(chars, phi, out);
    window_kernel<<<Bn / RB, 256, 0, stream>>>(chars, phi, out);
    window_kernel<<<Bn / RB, 256, 0, stream>>>(chars, phi, out);
}